// Round 6
// baseline (3639.175 us; speedup 1.0000x reference)
//
#include <hip/hip_runtime.h>

#define NB 131072
#define HD 100

typedef float f2 __attribute__((ext_vector_type(2)));

// ---------------------------------------------------------------------------
// Kernel 1 (PRODUCER, promoted from round-5 A/B win): 4 GCN layers.
// Block = 512 threads = 8 waves over the SAME 8 batches; wave wv owns 14
// output cols at j0 = min(wv*14, 86) (tail overlap writes bitwise-identical
// values). VGPR=32 -> 4 blocks/CU = 32 waves/CU (~90% occupancy).
// Weights via readfirstlane-uniform j0 -> s_load (SMEM) stream.
// ---------------------------------------------------------------------------
__global__ void __launch_bounds__(512, 8)
k_gcn3(const float* feat, const float* adj,
       const float* gc1w, const float* gc1b,
       const float* gc2w, const float* gc2b,
       const float* gc3w, const float* gc3b,
       const float* gc4w, const float* gc4b,
       float* gA, float* gB)
{
    __shared__ float hsh[64][102];   // 26112 B
    const int tid  = threadIdx.x;
    const int wv   = tid >> 6;
    const int lane = tid & 63;
    const int j0   = __builtin_amdgcn_readfirstlane(wv * 14 > 86 ? 86 : wv * 14);
    const int b    = lane >> 3;
    const int i    = lane & 7;
    const int batch = blockIdx.x * 8 + b;
    const int r    = lane;

    float adjr[8];
    {
        const float4 a0 = *(const float4*)(adj + (size_t)batch * 64 + i * 8);
        const float4 a1 = *(const float4*)(adj + (size_t)batch * 64 + i * 8 + 4);
        adjr[0] = a0.x; adjr[1] = a0.y; adjr[2] = a0.z; adjr[3] = a0.w;
        adjr[4] = a1.x; adjr[5] = a1.y; adjr[6] = a1.z; adjr[7] = a1.w;
    }
    int pidx[8];
#pragma unroll
    for (int m = 0; m < 8; m++) pidx[m] = ((lane & 0x38) | m) << 2;

    f2 t[7];

    // ---- gc1 ----
    {
        float f8[8];
        const float4 f0v = *(const float4*)(feat + (size_t)batch * 64 + i * 8);
        const float4 f1v = *(const float4*)(feat + (size_t)batch * 64 + i * 8 + 4);
        f8[0] = f0v.x; f8[1] = f0v.y; f8[2] = f0v.z; f8[3] = f0v.w;
        f8[4] = f1v.x; f8[5] = f1v.y; f8[6] = f1v.z; f8[7] = f1v.w;
#pragma unroll
        for (int jj = 0; jj < 7; jj++) t[jj] = (f2){0.f, 0.f};
#pragma unroll
        for (int k = 0; k < 8; k++) {
            const float* wr = gc1w + k * HD + j0;
            const f2 hk = {f8[k], f8[k]};
#pragma unroll
            for (int jj = 0; jj < 7; jj++)
                t[jj] = __builtin_elementwise_fma(hk, *(const f2*)(wr + 2 * jj), t[jj]);
        }
#pragma unroll
        for (int jj = 0; jj < 7; jj++) {
            f2 acc = *(const f2*)(gc1b + j0 + 2 * jj);
#pragma unroll
            for (int m = 0; m < 8; m++) {
                f2 tm;
                tm.x = __int_as_float(
                    __builtin_amdgcn_ds_bpermute(pidx[m], __float_as_int(t[jj].x)));
                tm.y = __int_as_float(
                    __builtin_amdgcn_ds_bpermute(pidx[m], __float_as_int(t[jj].y)));
                const f2 am = {adjr[m], adjr[m]};
                acc = __builtin_elementwise_fma(am, tm, acc);
            }
            f2 hv; hv.x = fmaxf(acc.x, 0.f); hv.y = fmaxf(acc.y, 0.f);
            *(f2*)&hsh[r][j0 + 2 * jj] = hv;
        }
    }
    __syncthreads();

    // ---- gc2..gc4 ----
    for (int l = 0; l < 3; l++) {
        const float* W  = (l == 0) ? gc2w : (l == 1) ? gc3w : gc4w;
        const float* Bb = (l == 0) ? gc2b : (l == 1) ? gc3b : gc4b;
#pragma unroll
        for (int jj = 0; jj < 7; jj++) t[jj] = (f2){0.f, 0.f};
#pragma unroll 2
        for (int k = 0; k < HD; k += 2) {
            const f2 h2 = *(const f2*)&hsh[r][k];
            const float* w0 = W + k * HD + j0;
            const float* w1 = w0 + HD;
            const f2 hx = {h2.x, h2.x};
            const f2 hy = {h2.y, h2.y};
#pragma unroll
            for (int jj = 0; jj < 7; jj++)
                t[jj] = __builtin_elementwise_fma(hx, *(const f2*)(w0 + 2 * jj), t[jj]);
#pragma unroll
            for (int jj = 0; jj < 7; jj++)
                t[jj] = __builtin_elementwise_fma(hy, *(const f2*)(w1 + 2 * jj), t[jj]);
        }
        __syncthreads();
#pragma unroll
        for (int jj = 0; jj < 7; jj++) {
            f2 acc = *(const f2*)(Bb + j0 + 2 * jj);
#pragma unroll
            for (int m = 0; m < 8; m++) {
                f2 tm;
                tm.x = __int_as_float(
                    __builtin_amdgcn_ds_bpermute(pidx[m], __float_as_int(t[jj].x)));
                tm.y = __int_as_float(
                    __builtin_amdgcn_ds_bpermute(pidx[m], __float_as_int(t[jj].y)));
                const f2 am = {adjr[m], adjr[m]};
                acc = __builtin_elementwise_fma(am, tm, acc);
            }
            f2 hv; hv.x = fmaxf(acc.x, 0.f); hv.y = fmaxf(acc.y, 0.f);
            *(f2*)&hsh[r][j0 + 2 * jj] = hv;
        }
        __syncthreads();
    }

    for (int idx = tid; idx < 8 * HD; idx += 512) {
        const int bl = idx / HD;
        const int j  = idx - bl * HD;
        const float v = hsh[bl * 8 + 7][j];
        const int gb = blockIdx.x * 8 + bl;
        if (j < 64) gA[(size_t)gb * 64 + j] = v;
        else        gB[(size_t)gb * 64 + (j - 64)] = v;
    }
}

// ---------------------------------------------------------------------------
// Kernel 1-A/B (CANDIDATE k_gcn4): identical to k_gcn3 EXCEPT j0 is NOT
// readfirstlane'd. The compiler cannot prove wv uniform -> weight addresses
// are "divergent" VGPR addresses -> global_load (VMEM, vmcnt) instead of
// s_load (SMEM, imprecise lgkmcnt). All 64 lanes load the same address, so
// HW coalesces to one request + broadcast. Theory: decouples weight latency
// from the ds_read h stream (no more lgkmcnt(0) full drains per k-step).
// Runs on 1/4 of the grid (timing sample only; output overwritten).
// ---------------------------------------------------------------------------
__global__ void __launch_bounds__(512, 8)
k_gcn4(const float* feat, const float* adj,
       const float* gc1w, const float* gc1b,
       const float* gc2w, const float* gc2b,
       const float* gc3w, const float* gc3b,
       const float* gc4w, const float* gc4b,
       float* gA, float* gB)
{
    __shared__ float hsh[64][102];
    const int tid  = threadIdx.x;
    const int wv   = tid >> 6;
    const int lane = tid & 63;
    const int j0   = wv * 14 > 86 ? 86 : wv * 14;   // divergent on purpose
    const int b    = lane >> 3;
    const int i    = lane & 7;
    const int batch = blockIdx.x * 8 + b;
    const int r    = lane;

    float adjr[8];
    {
        const float4 a0 = *(const float4*)(adj + (size_t)batch * 64 + i * 8);
        const float4 a1 = *(const float4*)(adj + (size_t)batch * 64 + i * 8 + 4);
        adjr[0] = a0.x; adjr[1] = a0.y; adjr[2] = a0.z; adjr[3] = a0.w;
        adjr[4] = a1.x; adjr[5] = a1.y; adjr[6] = a1.z; adjr[7] = a1.w;
    }
    int pidx[8];
#pragma unroll
    for (int m = 0; m < 8; m++) pidx[m] = ((lane & 0x38) | m) << 2;

    f2 t[7];

    {
        float f8[8];
        const float4 f0v = *(const float4*)(feat + (size_t)batch * 64 + i * 8);
        const float4 f1v = *(const float4*)(feat + (size_t)batch * 64 + i * 8 + 4);
        f8[0] = f0v.x; f8[1] = f0v.y; f8[2] = f0v.z; f8[3] = f0v.w;
        f8[4] = f1v.x; f8[5] = f1v.y; f8[6] = f1v.z; f8[7] = f1v.w;
#pragma unroll
        for (int jj = 0; jj < 7; jj++) t[jj] = (f2){0.f, 0.f};
#pragma unroll
        for (int k = 0; k < 8; k++) {
            const float* wr = gc1w + k * HD + j0;
            const f2 hk = {f8[k], f8[k]};
#pragma unroll
            for (int jj = 0; jj < 7; jj++)
                t[jj] = __builtin_elementwise_fma(hk, *(const f2*)(wr + 2 * jj), t[jj]);
        }
#pragma unroll
        for (int jj = 0; jj < 7; jj++) {
            f2 acc = *(const f2*)(gc1b + j0 + 2 * jj);
#pragma unroll
            for (int m = 0; m < 8; m++) {
                f2 tm;
                tm.x = __int_as_float(
                    __builtin_amdgcn_ds_bpermute(pidx[m], __float_as_int(t[jj].x)));
                tm.y = __int_as_float(
                    __builtin_amdgcn_ds_bpermute(pidx[m], __float_as_int(t[jj].y)));
                const f2 am = {adjr[m], adjr[m]};
                acc = __builtin_elementwise_fma(am, tm, acc);
            }
            f2 hv; hv.x = fmaxf(acc.x, 0.f); hv.y = fmaxf(acc.y, 0.f);
            *(f2*)&hsh[r][j0 + 2 * jj] = hv;
        }
    }
    __syncthreads();

    for (int l = 0; l < 3; l++) {
        const float* W  = (l == 0) ? gc2w : (l == 1) ? gc3w : gc4w;
        const float* Bb = (l == 0) ? gc2b : (l == 1) ? gc3b : gc4b;
#pragma unroll
        for (int jj = 0; jj < 7; jj++) t[jj] = (f2){0.f, 0.f};
#pragma unroll 2
        for (int k = 0; k < HD; k += 2) {
            const f2 h2 = *(const f2*)&hsh[r][k];
            const float* w0 = W + k * HD + j0;
            const float* w1 = w0 + HD;
            const f2 hx = {h2.x, h2.x};
            const f2 hy = {h2.y, h2.y};
#pragma unroll
            for (int jj = 0; jj < 7; jj++)
                t[jj] = __builtin_elementwise_fma(hx, *(const f2*)(w0 + 2 * jj), t[jj]);
#pragma unroll
            for (int jj = 0; jj < 7; jj++)
                t[jj] = __builtin_elementwise_fma(hy, *(const f2*)(w1 + 2 * jj), t[jj]);
        }
        __syncthreads();
#pragma unroll
        for (int jj = 0; jj < 7; jj++) {
            f2 acc = *(const f2*)(Bb + j0 + 2 * jj);
#pragma unroll
            for (int m = 0; m < 8; m++) {
                f2 tm;
                tm.x = __int_as_float(
                    __builtin_amdgcn_ds_bpermute(pidx[m], __float_as_int(t[jj].x)));
                tm.y = __int_as_float(
                    __builtin_amdgcn_ds_bpermute(pidx[m], __float_as_int(t[jj].y)));
                const f2 am = {adjr[m], adjr[m]};
                acc = __builtin_elementwise_fma(am, tm, acc);
            }
            f2 hv; hv.x = fmaxf(acc.x, 0.f); hv.y = fmaxf(acc.y, 0.f);
            *(f2*)&hsh[r][j0 + 2 * jj] = hv;
        }
        __syncthreads();
    }

    for (int idx = tid; idx < 8 * HD; idx += 512) {
        const int bl = idx / HD;
        const int j  = idx - bl * HD;
        const float v = hsh[bl * 8 + 7][j];
        const int gb = blockIdx.x * 8 + bl;
        if (j < 64) gA[(size_t)gb * 64 + j] = v;
        else        gB[(size_t)gb * 64 + (j - 64)] = v;
    }
}

// ---------------------------------------------------------------------------
// Kernel 2: head MLPs. Same math as the validated version; only change is
// j14/j4 no longer readfirstlane'd (semantics identical, pushes weights to
// the VMEM path per the same lgkmcnt-serialization theory).
// ---------------------------------------------------------------------------
template<int NPK, bool RELU>
__device__ __forceinline__ void dense_slice(const float* inRow, int K,
    const float* W, int ldw, const float* Bias,
    float* outPtr, int outStride, int bIdx, int j0)
{
    f2 acc[NPK];
#pragma unroll
    for (int jj = 0; jj < NPK; jj++) acc[jj] = (f2){0.f, 0.f};
#pragma unroll 2
    for (int k = 0; k < K; k += 2) {
        const f2 v = *(const f2*)(inRow + k);
        const float* w0 = W + k * ldw + j0;
        const float* w1 = w0 + ldw;
        const f2 vx = {v.x, v.x};
        const f2 vy = {v.y, v.y};
#pragma unroll
        for (int jj = 0; jj < NPK; jj++)
            acc[jj] = __builtin_elementwise_fma(vx, *(const f2*)(w0 + 2 * jj), acc[jj]);
#pragma unroll
        for (int jj = 0; jj < NPK; jj++)
            acc[jj] = __builtin_elementwise_fma(vy, *(const f2*)(w1 + 2 * jj), acc[jj]);
    }
#pragma unroll
    for (int jj = 0; jj < NPK; jj++) {
        const f2 bz = *(const f2*)(Bias + j0 + 2 * jj);
        f2 z; z.x = acc[jj].x + bz.x; z.y = acc[jj].y + bz.y;
        if (RELU) { z.x = fmaxf(z.x, 0.f); z.y = fmaxf(z.y, 0.f); }
        *(f2*)(outPtr + bIdx * outStride + j0 + 2 * jj) = z;
    }
}

__global__ void __launch_bounds__(512, 4)
k_head(const float* hw_emb, const float* gA, const float* gB,
       const float* fc3w, const float* fc3b, const float* fc4w, const float* fc4b,
       const float* fc5w, const float* fc5b,
       const float* f0w, const float* f0b, const float* f1w, const float* f1b,
       const float* f2w, const float* f2b, const float* f3w, const float* f3b,
       const float* f4w, const float* f4b,
       const float* e0w, const float* e0b, const float* e1w, const float* e1b,
       float* out)
{
    __shared__ float bufA[64][102];
    __shared__ float bufB[64][102];
    __shared__ float xcat[64][44];
    __shared__ float hwe[64][20];
    const int tid  = threadIdx.x;
    const int wv   = tid >> 6;
    const int b    = tid & 63;
    const int base = blockIdx.x * 64;
    const int j14 = wv * 14 > 86 ? 86 : wv * 14;   // divergent on purpose
    const int j4  = wv * 4 > 16 ? 16 : wv * 4;     // divergent on purpose

    if (tid < 320) {
        const float4 v = *(const float4*)(hw_emb + (size_t)base * 20 + tid * 4);
        const int bb = (tid * 4) / 20, kk = (tid * 4) % 20;
        *(float4*)&hwe[bb][kk] = v;
    }
    for (int q = tid; q < 64 * 32; q += 512) {
        const int bb = q >> 5, k2 = (q & 31) * 2;
        const float2 v = *(const float2*)(gA + (size_t)(base + bb) * 64 + k2);
        *(float2*)&bufA[bb][k2] = v;
    }
    for (int q = tid; q < 64 * 18; q += 512) {
        const int bb = q / 18, k2 = (q - bb * 18) * 2;
        const float2 v = *(const float2*)(gB + (size_t)(base + bb) * 64 + k2);
        *(float2*)&bufA[bb][64 + k2] = v;
    }
    __syncthreads();

    dense_slice<7, true >(&hwe[b][0], 20, e0w, HD, e0b, &bufB[0][0], 102, b, j14);
    __syncthreads();
    dense_slice<2, true >(&bufB[b][0], HD, e1w, 20, e1b, &xcat[0][20], 44, b, j4);
    __syncthreads();
    dense_slice<7, true >(&bufA[b][0], HD, fc3w, HD, fc3b, &bufB[0][0], 102, b, j14);
    __syncthreads();
    dense_slice<7, true >(&bufB[b][0], HD, fc4w, HD, fc4b, &bufA[0][0], 102, b, j14);
    __syncthreads();
    dense_slice<2, false>(&bufA[b][0], HD, fc5w, 20, fc5b, &xcat[0][0], 44, b, j4);
    __syncthreads();
    dense_slice<7, true >(&xcat[b][0], 40, f0w, HD, f0b, &bufA[0][0], 102, b, j14);
    __syncthreads();
    dense_slice<7, true >(&bufA[b][0], HD, f1w, HD, f1b, &bufB[0][0], 102, b, j14);
    __syncthreads();
    dense_slice<7, true >(&bufB[b][0], HD, f2w, HD, f2b, &bufA[0][0], 102, b, j14);
    __syncthreads();
    dense_slice<7, true >(&bufA[b][0], HD, f3w, HD, f3b, &bufB[0][0], 102, b, j14);
    __syncthreads();
    if (wv == 0) {
        float z = f4b[0];
        const float* row = &bufB[b][0];
#pragma unroll 2
        for (int k = 0; k < HD; k += 2) {
            const float2 v = *(const float2*)(row + k);
            z = fmaf(v.x, f4w[k], z);
            z = fmaf(v.y, f4w[k + 1], z);
        }
        out[base + b] = 1.f / (1.f + __expf(-z));
    }
}

// ---------------------------------------------------------------------------
extern "C" void kernel_launch(void* const* d_in, const int* in_sizes, int n_in,
                              void* d_out, int out_size, void* d_ws, size_t ws_size,
                              hipStream_t stream)
{
    const float* feat = (const float*)d_in[0];
    const float* adj  = (const float*)d_in[1];
    const float* hw   = (const float*)d_in[2];
    const float* gc1w = (const float*)d_in[3];
    const float* gc1b = (const float*)d_in[4];
    const float* gc2w = (const float*)d_in[5];
    const float* gc2b = (const float*)d_in[6];
    const float* gc3w = (const float*)d_in[7];
    const float* gc3b = (const float*)d_in[8];
    const float* gc4w = (const float*)d_in[9];
    const float* gc4b = (const float*)d_in[10];
    const float* fc3w = (const float*)d_in[11];
    const float* fc3b = (const float*)d_in[12];
    const float* fc4w = (const float*)d_in[13];
    const float* fc4b = (const float*)d_in[14];
    const float* fc5w = (const float*)d_in[15];
    const float* fc5b = (const float*)d_in[16];
    const float* f0w  = (const float*)d_in[17];
    const float* f0b  = (const float*)d_in[18];
    const float* f1w  = (const float*)d_in[19];
    const float* f1b  = (const float*)d_in[20];
    const float* f2w  = (const float*)d_in[21];
    const float* f2b  = (const float*)d_in[22];
    const float* f3w  = (const float*)d_in[23];
    const float* f3b  = (const float*)d_in[24];
    const float* f4w  = (const float*)d_in[25];
    const float* f4b  = (const float*)d_in[26];
    const float* e0w  = (const float*)d_in[27];
    const float* e0b  = (const float*)d_in[28];
    const float* e1w  = (const float*)d_in[29];
    const float* e1b  = (const float*)d_in[30];

    const size_t need = (size_t)NB * 128 * sizeof(float);
    if (ws_size >= need) {
        float* gAp = (float*)d_ws;
        float* gBp = (float*)d_ws + (size_t)NB * 64;
        // A/B candidate on 1/4 grid (timing sample; output overwritten below)
        hipLaunchKernelGGL(k_gcn4, dim3(NB / 32), dim3(512), 0, stream,
                           feat, adj, gc1w, gc1b, gc2w, gc2b, gc3w, gc3b, gc4w, gc4b,
                           gAp, gBp);
        // Producer (validated structure)
        hipLaunchKernelGGL(k_gcn3, dim3(NB / 8), dim3(512), 0, stream,
                           feat, adj, gc1w, gc1b, gc2w, gc2b, gc3w, gc3b, gc4w, gc4b,
                           gAp, gBp);
        hipLaunchKernelGGL(k_head, dim3(NB / 64), dim3(512), 0, stream,
                           hw, gAp, gBp, fc3w, fc3b, fc4w, fc4b, fc5w, fc5b,
                           f0w, f0b, f1w, f1b, f2w, f2b, f3w, f3b, f4w, f4b,
                           e0w, e0b, e1w, e1b, (float*)d_out);
    } else {
        // Overlay fallback: producer only (gA/gB overlaid into feat/adj; each
        // block writes only its own batches after consuming them).
        float* gAp = (float*)d_in[0];
        float* gBp = (float*)d_in[1];
        hipLaunchKernelGGL(k_gcn3, dim3(NB / 8), dim3(512), 0, stream,
                           feat, adj, gc1w, gc1b, gc2w, gc2b, gc3w, gc3b, gc4w, gc4b,
                           gAp, gBp);
        hipLaunchKernelGGL(k_head, dim3(NB / 64), dim3(512), 0, stream,
                           hw, gAp, gBp, fc3w, fc3b, fc4w, fc4b, fc5w, fc5b,
                           f0w, f0b, f1w, f1b, f2w, f2b, f3w, f3b, f4w, f4b,
                           e0w, e0b, e1w, e1b, (float*)d_out);
    }
}